// Round 3
// baseline (74.634 us; speedup 1.0000x reference)
//
#include <hip/hip_runtime.h>

// RankingLoss: loss = sum_{i,j} [c_i==0 && Y_j>Y_i] * relu(risk_j - risk_i) / count
// risk = sum(hazards[:, :4], axis=1). B = 8192, N_CLASSES = 4, MARGIN = 0.
//
// R2 design:
//  k1 rl_compact (1 block x 1024): compact uncensored i with Y<3 into class
//     buckets (padded to 64 with r=+1e30 sentinels), class histograms ->
//     exact pair count, per-group class table.
//  k2 rl_pairs: lane owns j (rj_a = (Yj>a)?rj:-1e30 precomputed, a=0..2);
//     i-groups are uniform-class so inner loop is 4 VALU / 64 pairs:
//     d = rjc - ri; acc += max(d,0); ri = dpp wave_ror:1.  No LDS/SALU/branches.
//  k3 rl_final: sum 1024 partials, divide by exact count.
// Note: harness re-poisons the full 268MB ws every iter (~40us fill) - fixed cost.

#define B_SIZE 8192
#define BLOCK  256
#define JT     (B_SIZE / BLOCK)   // 32 j-tiles
#define GY     32                 // y-dim blocks (grid-stride over i-groups)
#define NPSUM  (JT * GY)          // 1024 partials

// ws layout (byte offsets)
#define CR_OFF    0        // float cr[8448] compacted+padded risks
#define GCLS_OFF  36864    // int gcls[160] class of each 64-wide i-group
#define SCAL_OFF  40960    // int scal[2]: [0]=NG (group count), [1]=pair count
#define PSUM_OFF  49152    // float psum[NPSUM]

__global__ __launch_bounds__(1024) void rl_compact(
    const float4* __restrict__ hz,
    const int*    __restrict__ Y,
    const int*    __restrict__ c,
    float* __restrict__ cr,
    int*   __restrict__ gcls,
    int*   __restrict__ scal)
{
    const int t    = threadIdx.x;
    const int lane = t & 63;

    float r[8]; int y[8]; bool keep[8];
    #pragma unroll
    for (int k = 0; k < 8; ++k) {
        const int e = k * 1024 + t;           // coalesced; compaction order is free
        const float4 h = hz[e];
        r[k] = (h.x + h.y) + (h.z + h.w);
        y[k] = Y[e];
        keep[k] = (c[e] == 0);
    }

    __shared__ int histA[4], histU[4], fill[4];
    __shared__ int sNG;
    if (t < 4) { histA[t] = 0; histU[t] = 0; }
    __syncthreads();

    // pass 1: histograms via per-wave ballots (no per-element atomics)
    int la[4] = {0,0,0,0}, lu[4] = {0,0,0,0};
    #pragma unroll
    for (int k = 0; k < 8; ++k) {
        #pragma unroll
        for (int cls = 0; cls < 4; ++cls) {
            const unsigned long long mA = __ballot(y[k] == cls);
            const unsigned long long mU = __ballot(keep[k] && (y[k] == cls));
            la[cls] += (int)__popcll(mA);
            lu[cls] += (int)__popcll(mU);
        }
    }
    if (lane == 0) {
        #pragma unroll
        for (int cls = 0; cls < 4; ++cls) {
            atomicAdd(&histA[cls], la[cls]);
            atomicAdd(&histU[cls], lu[cls]);
        }
    }
    __syncthreads();

    if (t == 0) {
        int suff[5]; suff[4] = 0;
        for (int a = 3; a >= 0; --a) suff[a] = suff[a + 1] + histA[a];
        long long cnt = 0;
        int off = 0, ng = 0;
        for (int a = 0; a < 3; ++a) {         // class 3 i's contribute nothing
            fill[a] = off;
            const int pad = (histU[a] + 63) & ~63;
            for (int g = 0; g < pad / 64; ++g) gcls[ng + g] = a;
            ng += pad / 64;
            off += pad;
            cnt += (long long)histU[a] * suff[a + 1];
        }
        cnt += (long long)histU[3] * suff[4]; // == 0, for clarity
        fill[3] = off;                        // unused bucket (class-3 dropped)
        sNG = ng;
        scal[0] = ng;
        scal[1] = (int)cnt;
    }
    __syncthreads();

    // sentinel-fill the padded region (real slots overwritten in pass 2)
    const int M = sNG * 64;
    for (int idx = t; idx < M; idx += 1024) cr[idx] = 1e30f;
    __syncthreads();

    // pass 2: bucketed compaction (wave-aggregated LDS atomics)
    #pragma unroll
    for (int k = 0; k < 8; ++k) {
        #pragma unroll
        for (int cls = 0; cls < 3; ++cls) {
            const bool mine = keep[k] && (y[k] == cls);
            const unsigned long long m = __ballot(mine);
            if (m == 0ull) continue;          // wave-uniform branch
            const int rank = (int)__popcll(m & ((1ull << lane) - 1ull));
            int base;
            if (lane == 0) base = atomicAdd(&fill[cls], (int)__popcll(m));
            base = __shfl(base, 0, 64);
            if (mine) cr[base + rank] = r[k];
        }
    }
}

__global__ __launch_bounds__(BLOCK) void rl_pairs(
    const float4* __restrict__ hz,
    const int*    __restrict__ Y,
    const float*  __restrict__ cr,
    const int*    __restrict__ gcls,
    const int*    __restrict__ scal,
    float*        __restrict__ psum)
{
    const int tid  = threadIdx.x;
    const int lane = tid & 63;

    const int j = blockIdx.x * BLOCK + tid;
    const float4 h = hz[j];
    const float rj = (h.x + h.y) + (h.z + h.w);
    const int   yj = Y[j];
    const float rj0 = (yj > 0) ? rj : -1e30f;
    const float rj1 = (yj > 1) ? rj : -1e30f;
    const float rj2 = (yj > 2) ? rj : -1e30f;

    const int NG = scal[0];
    float acc = 0.0f;

    for (int g = blockIdx.y; g < NG; g += GY) {
        const int cls = gcls[g];                          // uniform per block
        const float rjc = (cls == 0) ? rj0 : (cls == 1) ? rj1 : rj2;
        float ri = cr[g * 64 + lane];
        #pragma unroll
        for (int it = 0; it < 64; ++it) {
            const float d = rjc - ri;                     // sentinels kill masked terms
            acc += fmaxf(d, 0.0f);
            ri = __uint_as_float((unsigned)__builtin_amdgcn_mov_dpp(
                     (int)__float_as_uint(ri), 0x13C /*wave_ror:1*/, 0xF, 0xF, true));
        }
    }

    #pragma unroll
    for (int off = 32; off > 0; off >>= 1) acc += __shfl_down(acc, off, 64);
    __shared__ float sa[BLOCK / 64];
    if (lane == 0) sa[tid >> 6] = acc;
    __syncthreads();
    if (tid == 0)
        psum[blockIdx.y * JT + blockIdx.x] = (sa[0] + sa[1]) + (sa[2] + sa[3]);
}

__global__ __launch_bounds__(256) void rl_final(
    const float* __restrict__ psum,
    const int*   __restrict__ scal,
    float*       __restrict__ out)
{
    const int tid  = threadIdx.x;
    const int lane = tid & 63;
    float a = 0.0f;
    #pragma unroll
    for (int k = 0; k < NPSUM / 256; ++k) a += psum[k * 256 + tid];
    #pragma unroll
    for (int off = 32; off > 0; off >>= 1) a += __shfl_down(a, off, 64);
    __shared__ float sa[4];
    if (lane == 0) sa[tid >> 6] = a;
    __syncthreads();
    if (tid == 0) {
        const int n = scal[1];
        out[0] = (n > 0) ? ((sa[0] + sa[1]) + (sa[2] + sa[3])) / (float)n : 0.0f;
    }
}

extern "C" void kernel_launch(void* const* d_in, const int* in_sizes, int n_in,
                              void* d_out, int out_size, void* d_ws, size_t ws_size,
                              hipStream_t stream) {
    const float4* hz = (const float4*)d_in[0];  // hazards [8192 x 4] f32
    // d_in[1] = S, unused by the reference computation.
    const int* Y = (const int*)d_in[2];
    const int* c = (const int*)d_in[3];

    char* ws = (char*)d_ws;
    float* cr   = (float*)(ws + CR_OFF);
    int*   gcls = (int*)  (ws + GCLS_OFF);
    int*   scal = (int*)  (ws + SCAL_OFF);
    float* psum = (float*)(ws + PSUM_OFF);
    float* out  = (float*)d_out;

    rl_compact<<<1, 1024, 0, stream>>>(hz, Y, c, cr, gcls, scal);
    rl_pairs<<<dim3(JT, GY), BLOCK, 0, stream>>>(hz, Y, cr, gcls, scal, psum);
    rl_final<<<1, 256, 0, stream>>>(psum, scal, out);
}

// Round 4
// 67.168 us; speedup vs baseline: 1.1112x; 1.1112x over previous
//
#include <hip/hip_runtime.h>

// RankingLoss: loss = sum_{i,j} [c_i==0 && Y_j>Y_i] * relu(risk_j - risk_i) / count
// risk = sum(hazards[:, :4], axis=1). B = 8192, N_CLASSES = 4, MARGIN = 0.
//
// R3 design: TWO launches.
//  rl_all (grid 32 j-tiles x 32 i-chunks, 256 thr): each block class-compacts
//    its own 256-wide i-chunk in LDS (ballot + LDS-atomic, uncensored & Y<3,
//    padded to 64 with +1e30 sentinels), then pure-VALU pair loop: per class
//    group, d = rjc - ri; acc += max(d,0); ri = dpp wave_ror:1 (4 instr / 64
//    pairs, no LDS/SALU in loop). Exact pair count per block from class
//    histograms. Partials -> ws.
//  rl_final: reduce 1024 partials, divide.
// Fixed harness floor: 268MB ws re-poison fill ~40us/iter dominates total.

#define B_SIZE 8192
#define BLOCK  256
#define JT     (B_SIZE / BLOCK)      // 32 j-tiles
#define IC     (B_SIZE / BLOCK)      // 32 i-chunks
#define NBLK   (JT * IC)             // 1024 partials
#define CAP    128                   // per-class capacity within a 256-chunk (mean 32, 17 sigma)

__global__ __launch_bounds__(BLOCK) void rl_all(
    const float4* __restrict__ hz,   // hazards [B] as float4 rows
    const int*    __restrict__ Y,
    const int*    __restrict__ c,
    float*        __restrict__ psum,
    int*          __restrict__ pcnt)
{
    __shared__ float sPad[3 * CAP];  // class-bucketed risks, sentinel-padded
    __shared__ int   sCnt[3];        // per-class uncensored count in this i-chunk
    __shared__ int   sSuf[3];        // #{j in tile: yj > a}
    __shared__ float sA[BLOCK / 64];
    __shared__ int   sN[BLOCK / 64];

    const int tid  = threadIdx.x;
    const int lane = tid & 63;
    const int wave = tid >> 6;

    if (tid < 3) { sCnt[tid] = 0; sSuf[tid] = 0; }
    for (int k = tid; k < 3 * CAP; k += BLOCK) sPad[k] = 1e30f;

    // ---- j side: this thread's own column ----
    const int j = blockIdx.x * BLOCK + tid;
    const float4 hj = hz[j];
    const float rj = (hj.x + hj.y) + (hj.z + hj.w);
    const int   yj = Y[j];

    // ---- i side: this thread's own row in the block's i-chunk ----
    const int i = blockIdx.y * BLOCK + tid;
    const float4 hi = hz[i];
    const float ri0 = (hi.x + hi.y) + (hi.z + hi.w);
    const int   yi = Y[i];
    const bool  keep = (c[i] == 0);

    __syncthreads();   // sentinel fill + counter init visible

    // ---- compact i-chunk into class buckets; j suffix histogram ----
    #pragma unroll
    for (int cls = 0; cls < 3; ++cls) {
        const bool mine = keep && (yi == cls);
        const unsigned long long m = __ballot(mine);
        if (m) {                                     // wave-uniform
            const int pop  = (int)__popcll(m);
            const int rank = (int)__popcll(m & ((1ull << lane) - 1ull));
            int base;
            if (lane == 0) base = atomicAdd(&sCnt[cls], pop);
            base = __shfl(base, 0, 64);
            const int slot = base + rank;
            if (mine && slot < CAP) sPad[cls * CAP + slot] = ri0;
        }
        const unsigned long long mj = __ballot(yj > cls);
        if (lane == 0 && mj) atomicAdd(&sSuf[cls], (int)__popcll(mj));
    }
    __syncthreads();

    const float rj0 = (yj > 0) ? rj : -1e30f;
    const float rj1 = (yj > 1) ? rj : -1e30f;
    const float rj2 = (yj > 2) ? rj : -1e30f;

    // ---- pure-VALU pair loop: 4 instr per 64 pairs ----
    float acc = 0.0f;
    #pragma unroll
    for (int cls = 0; cls < 3; ++cls) {
        const float rjc = (cls == 0) ? rj0 : (cls == 1) ? rj1 : rj2;
        const int n = min(sCnt[cls], CAP);
        for (int g = 0; g * 64 < n; ++g) {           // uniform trip count
            float ri = sPad[cls * CAP + g * 64 + lane];
            #pragma unroll
            for (int it = 0; it < 64; ++it) {
                acc += fmaxf(rjc - ri, 0.0f);        // sentinels kill masked terms
                ri = __uint_as_float((unsigned)__builtin_amdgcn_mov_dpp(
                         (int)__float_as_uint(ri), 0x13C /*wave_ror:1*/, 0xF, 0xF, true));
            }
        }
    }

    // ---- block reduction -> one partial (sum + exact count) per block ----
    #pragma unroll
    for (int off = 32; off > 0; off >>= 1) acc += __shfl_down(acc, off, 64);
    if (lane == 0) sA[wave] = acc;
    __syncthreads();
    if (tid == 0) {
        const int gid = blockIdx.y * JT + blockIdx.x;
        psum[gid] = (sA[0] + sA[1]) + (sA[2] + sA[3]);
        pcnt[gid] = sCnt[0] * sSuf[0] + sCnt[1] * sSuf[1] + sCnt[2] * sSuf[2];
    }
}

__global__ __launch_bounds__(256) void rl_final(
    const float* __restrict__ psum,
    const int*   __restrict__ pcnt,
    float*       __restrict__ out)
{
    const int tid  = threadIdx.x;
    const int lane = tid & 63;
    float a = 0.0f; int n = 0;
    #pragma unroll
    for (int k = 0; k < NBLK / 256; ++k) {
        a += psum[k * 256 + tid];
        n += pcnt[k * 256 + tid];
    }
    #pragma unroll
    for (int off = 32; off > 0; off >>= 1) {
        a += __shfl_down(a, off, 64);
        n += __shfl_down(n, off, 64);
    }
    __shared__ float sa[4];
    __shared__ int   sc[4];
    if (lane == 0) { sa[tid >> 6] = a; sc[tid >> 6] = n; }
    __syncthreads();
    if (tid == 0) {
        const float A = (sa[0] + sa[1]) + (sa[2] + sa[3]);
        const int   N = (sc[0] + sc[1]) + (sc[2] + sc[3]);
        out[0] = (N > 0) ? (A / (float)N) : 0.0f;
    }
}

extern "C" void kernel_launch(void* const* d_in, const int* in_sizes, int n_in,
                              void* d_out, int out_size, void* d_ws, size_t ws_size,
                              hipStream_t stream) {
    const float4* hz = (const float4*)d_in[0];  // hazards [8192 x 4] f32
    // d_in[1] = S, unused by the reference computation.
    const int* Y = (const int*)d_in[2];
    const int* c = (const int*)d_in[3];

    float* psum = (float*)d_ws;                 // [1024]
    int*   pcnt = (int*)d_ws + NBLK;            // [1024]
    float* out  = (float*)d_out;

    rl_all<<<dim3(JT, IC), BLOCK, 0, stream>>>(hz, Y, c, psum, pcnt);
    rl_final<<<1, 256, 0, stream>>>(psum, pcnt, out);
}